// Round 10
// baseline (14496.967 us; speedup 1.0000x reference)
//
#include <hip/hip_runtime.h>
#include <stdint.h>

// 3-layer LSTM (H=256, B=256, T=512), persistent pipelined kernel — R11 RESTRUCTURE.
//
// After 6 null micro-experiments (R5-R10: bank conflicts, coalescing, flag RMW,
// WG packing, prefetch, register pressure — all individually cleared with zero
// dur effect), the ~8800cy beat is attributed to the STRUCTURE: own-h recurrence
// and an 8-WG all-to-all join both crossed the LLC every step (store->flag->
// observe->load, 4-5 serialized ~500-700cy hops).
//
// New decomposition: WG = (layer, batch-group of 16 rows) -> 48 WGs x 1024 thr
// (16 waves). Each WG computes ALL 256 units for its 16 rows:
//  - own-h recurrence is WG-INTERNAL (h in LDS, barriers only; no LLC hop).
//  - only cross-WG edge: layer handoff l->l+1, 1:1 SPSC ring (RING=4) with
//    plain relaxed agent-scope store flags (no atomics, no joins).
//  - wave w owns units [w*16, w*16+16) x 4 gates = 64 W-rows x K=512 as MFMA
//    B-fragments (256 VGPR/lane; 4 waves/SIMD @ <=512 VGPR/lane).
//  - combine is fully LANE-LOCAL: acc tiles tau=0..3 put (row,unit)'s i,f,g,o
//    in the same lane -> no gl[] LDS exchange, no combine barrier.
//  - h tiles in LDS are XOR-swizzled (byte ^= (row&7)<<4, both sides) to kill
//    the row-stride-512B bank conflict on ds_read_b128 A-fragments.
// Cost: compute on 48 CUs -> ~256 MFMA/SIMD/step ~ 1280cy; est beat 2800-3500cy
// vs measured 8800.  MFMA layout identical to the proven kernel (A row=l15,
// B n=l15, k=quad*8; C row=quad*4+reg, col=l15).

#define Hd 256
#define Bd 256
#define Td 512
#define RING 4
#define NG 16     // batch groups
#define RPG 16    // rows per group
#define CSP 16    // uints spacing between flags (64 B)
#define TILE (RPG * Hd)   // 4096 bf16 = 8192 B per ring slot

typedef __attribute__((ext_vector_type(8))) short short8;
typedef __attribute__((ext_vector_type(4))) float floatx4;

__device__ __forceinline__ unsigned short f2bf(float f) {
  union { float f; unsigned int u; } v; v.f = f;
  return (unsigned short)((v.u + 0x7fffu + ((v.u >> 16) & 1u)) >> 16);
}
__device__ __forceinline__ float sigm(float x) { return 1.0f / (1.0f + __expf(-x)); }
__device__ __forceinline__ float tanhfast(float x) { return 2.0f / (1.0f + __expf(-2.0f * x)) - 1.0f; }

__device__ __forceinline__ void spin_relaxed(unsigned int* p, unsigned int v) {
  while (__hip_atomic_load(p, __ATOMIC_RELAXED, __HIP_MEMORY_SCOPE_AGENT) < v) { }
}

__global__ __launch_bounds__(1024, 1) void lstm3_kernel(
    const float* __restrict__ xin,
    const float* __restrict__ Wi1, const float* __restrict__ Wh1,
    const float* __restrict__ bi1, const float* __restrict__ bh1,
    const float* __restrict__ Wi2, const float* __restrict__ Wh2,
    const float* __restrict__ bi2, const float* __restrict__ bh2,
    const float* __restrict__ Wi3, const float* __restrict__ Wh3,
    const float* __restrict__ bi3, const float* __restrict__ bh3,
    const float* __restrict__ Wlin, const float* __restrict__ blin,
    float* __restrict__ out,                // [B][T], pre-zeroed
    unsigned int* __restrict__ cnt,         // flags: prod @0, cons @1024 (uints)
    unsigned short* __restrict__ ring)      // [3][NG][RING][RPG][Hd] bf16
{
  __shared__ char ownraw[8192];   // h(t-1) [16 rows][256 units] bf16, XOR-swizzled
  __shared__ char upraw[8192];    // up-h(t) staging, same layout

  const int bid = blockIdx.x;
  const int l   = bid >> 4;       // layer 0..2
  const int g   = bid & 15;       // batch group 0..15 (chain (0..2,g) ≡ g mod 8 -> same XCD)

  const int tid   = threadIdx.x;
  const int lane  = tid & 63;
  const int wavei = tid >> 6;     // 0..15
  const int quad  = lane >> 4;
  const int l15   = lane & 15;
  const int u0    = wavei << 4;
  const int unit  = u0 + l15;     // this lane's hidden unit (combine + B-frag col)
  const int rbase = g * RPG;

  const float* Wih = (l == 1) ? Wi2 : Wi3;               // l==0: unused in MFMA
  const float* Whh = (l == 0) ? Wh1 : ((l == 1) ? Wh2 : Wh3);
  const float* bi  = (l == 0) ? bi1 : ((l == 1) ? bi2 : bi3);
  const float* bh  = (l == 0) ? bh1 : ((l == 1) ? bh2 : bh3);

  // ---- one-time: weight slices -> bf16 B-fragments (256 VGPRs/lane) ----
  // breg[tau][kc]: W[n = tau*256+unit][k = kc*32 + quad*8 + e]; kc<8 = up-h (Wih),
  // kc>=8 = own-h (Whh, k-256).
  short8 breg[4][16];
  #pragma unroll
  for (int tau = 0; tau < 4; ++tau) {
    const int n = tau * Hd + unit;
    #pragma unroll
    for (int kc = 0; kc < 16; ++kc) {
      short8 v = {0, 0, 0, 0, 0, 0, 0, 0};
      const float* src = nullptr;
      if (kc < 8) { if (l != 0) src = Wih + (size_t)n * Hd + kc * 32 + quad * 8; }
      else        { src = Whh + (size_t)n * Hd + (kc - 8) * 32 + quad * 8; }
      if (src) {
        #pragma unroll
        for (int e = 0; e < 8; ++e) v[e] = (short)f2bf(src[e]);
      }
      breg[tau][kc] = v;
    }
  }

  // ---- combine constants (lane-local: one unit, 4 rows) ----
  float bsum[4], wiv[4];
  #pragma unroll
  for (int tau = 0; tau < 4; ++tau) {
    bsum[tau] = bi[tau * Hd + unit] + bh[tau * Hd + unit];
    wiv[tau]  = (l == 0) ? Wi1[tau * Hd + unit] : 0.0f;
  }
  const float wlv = (l == 2) ? Wlin[unit] : 0.0f;
  const float bl0 = (l == 2) ? blin[0] : 0.0f;

  // ---- flags (SPSC): prod[l][g] = steps produced; cons[l][g] = up-steps consumed ----
  unsigned int* prodMe = cnt + (l * NG + g) * CSP;
  unsigned int* prodUp = cnt + ((l - 1) * NG + g) * CSP;          // deref only if l>0
  unsigned int* consMe = cnt + 1024 + (l * NG + g) * CSP;
  unsigned int* consDn = cnt + 1024 + ((l + 1) * NG + g) * CSP;   // deref only if l<2

  unsigned short* ringMe = ring + (size_t)(l * NG + g) * RING * TILE;
  const unsigned short* ringUp = ring + (size_t)((l - 1) * NG + g) * RING * TILE;

  // staging: thread -> 8 B of the up tile; LDS dest swizzled
  const int srow = tid >> 6;
  const int sw   = (tid & 63) * 8;
  const int sdst = srow * 512 + (sw ^ ((srow & 7) << 4));

  // zero own-h so t==0 sees h(-1)=0 (ordered by first top barrier)
  *(unsigned long long*)(ownraw + tid * 8) = 0ull;

  float cst[4] = {0.f, 0.f, 0.f, 0.f};

  for (int t = 0; t < Td; ++t) {
    // ---- waits: tid1 = up available; tid2 = down ring credit ----
    if (tid == 1)      { if (l != 0) spin_relaxed(prodUp, (unsigned)(t + 1)); }
    else if (tid == 2) { if (l != 2 && t >= RING) spin_relaxed(consDn, (unsigned)(t - RING + 1)); }
    __syncthreads();

    // ---- issue up-h ring loads (overlap with own-half MFMA) ----
    unsigned long long upd = 0ull;
    if (l != 0) {
      const char* src = (const char*)(ringUp + (size_t)(t & 3) * TILE) + tid * 8;
      asm volatile("global_load_dwordx2 %0, %1, off sc0 sc1" : "=&v"(upd) : "v"(src));
    }
    float xv[4];
    if (l == 0) {
      #pragma unroll
      for (int r = 0; r < 4; ++r) xv[r] = xin[(size_t)(rbase + quad * 4 + r) * Td + t];
    }

    floatx4 acc[4];
    #pragma unroll
    for (int tau = 0; tau < 4; ++tau) acc[tau] = floatx4{0.f, 0.f, 0.f, 0.f};

    // ---- own half (k>=256): A from ownraw (swizzled), B = breg[tau][8+kc] ----
    #pragma unroll
    for (int kc = 0; kc < 8; ++kc) {
      const short8 a = *reinterpret_cast<const short8*>(
          ownraw + l15 * 512 + ((kc * 64 + quad * 16) ^ ((l15 & 7) << 4)));
      #pragma unroll
      for (int tau = 0; tau < 4; ++tau)
        acc[tau] = __builtin_amdgcn_mfma_f32_16x16x32_bf16(a, breg[tau][8 + kc], acc[tau], 0, 0, 0);
    }

    // ---- stage up tile, publish consumption, up half (k<256) ----
    if (l != 0) {
      asm volatile("s_waitcnt vmcnt(0)" ::: "memory");
      *(unsigned long long*)(upraw + sdst) = upd;
      __syncthreads();   // also: all own-h reads complete before h writes below
      if (tid == 0)
        __hip_atomic_store(consMe, (unsigned)(t + 1), __ATOMIC_RELAXED, __HIP_MEMORY_SCOPE_AGENT);
      #pragma unroll
      for (int kc = 0; kc < 8; ++kc) {
        const short8 a = *reinterpret_cast<const short8*>(
            upraw + l15 * 512 + ((kc * 64 + quad * 16) ^ ((l15 & 7) << 4)));
        #pragma unroll
        for (int tau = 0; tau < 4; ++tau)
          acc[tau] = __builtin_amdgcn_mfma_f32_16x16x32_bf16(a, breg[tau][kc], acc[tau], 0, 0, 0);
      }
    } else {
      __syncthreads();   // own-h reads complete before h writes below
    }

    // ---- combine: fully lane-local (4 rows x 1 unit) ----
    float hv[4];
    #pragma unroll
    for (int r = 0; r < 4; ++r) {
      float pi = acc[0][r] + bsum[0];
      float pf = acc[1][r] + bsum[1];
      float pg = acc[2][r] + bsum[2];
      float po = acc[3][r] + bsum[3];
      if (l == 0) {
        pi += xv[r] * wiv[0]; pf += xv[r] * wiv[1];
        pg += xv[r] * wiv[2]; po += xv[r] * wiv[3];
      }
      const float ii = sigm(pi), ff = sigm(pf), gv = tanhfast(pg), oo = sigm(po);
      cst[r] = ff * cst[r] + ii * gv;
      hv[r] = oo * tanhfast(cst[r]);
    }

    // ---- write h(t) to own LDS (bf16, swizzled) for next step ----
    #pragma unroll
    for (int r = 0; r < 4; ++r) {
      const int row = quad * 4 + r;
      *(unsigned short*)(ownraw + row * 512 + ((unit * 2) ^ ((row & 7) << 4))) = f2bf(hv[r]);
    }

    if (l != 2) {
      // ---- ring store for downstream (pack pairs via shfl; linear layout) ----
      unsigned short* dstb = ringMe + (size_t)(t & 3) * TILE;
      #pragma unroll
      for (int r = 0; r < 4; ++r) {
        const float hn = __shfl_xor(hv[r], 1);
        if ((l15 & 1) == 0) {
          const int row = quad * 4 + r;
          const unsigned int packed = (unsigned int)f2bf(hv[r]) | ((unsigned int)f2bf(hn) << 16);
          __hip_atomic_store((unsigned int*)(dstb + row * Hd + unit), packed,
                             __ATOMIC_RELAXED, __HIP_MEMORY_SCOPE_AGENT);
        }
      }
    } else {
      // ---- output head: reduce over this wave's 16 units, atomicAdd across waves ----
      #pragma unroll
      for (int r = 0; r < 4; ++r) {
        float pr = wlv * hv[r];
        pr += __shfl_xor(pr, 1);
        pr += __shfl_xor(pr, 2);
        pr += __shfl_xor(pr, 4);
        pr += __shfl_xor(pr, 8);
        if (l15 == 0) {
          atomicAdd(&out[(size_t)(rbase + quad * 4 + r) * Td + t],
                    pr + (wavei == 0 ? bl0 : 0.0f));
        }
      }
    }

    __syncthreads();   // drains ring stores; orders ownraw writes for next step
    if (tid == 0 && l != 2)
      __hip_atomic_store(prodMe, (unsigned)(t + 1), __ATOMIC_RELAXED, __HIP_MEMORY_SCOPE_AGENT);
  }
}

extern "C" void kernel_launch(void* const* d_in, const int* in_sizes, int n_in,
                              void* d_out, int out_size, void* d_ws, size_t ws_size,
                              hipStream_t stream) {
  const float* xin  = (const float*)d_in[0];
  const float* Wi1  = (const float*)d_in[1];
  const float* Wh1  = (const float*)d_in[2];
  const float* bi1  = (const float*)d_in[3];
  const float* bh1  = (const float*)d_in[4];
  const float* Wi2  = (const float*)d_in[5];
  const float* Wh2  = (const float*)d_in[6];
  const float* bi2  = (const float*)d_in[7];
  const float* bh2  = (const float*)d_in[8];
  const float* Wi3  = (const float*)d_in[9];
  const float* Wh3  = (const float*)d_in[10];
  const float* bi3  = (const float*)d_in[11];
  const float* bh3  = (const float*)d_in[12];
  const float* Wlin = (const float*)d_in[13];
  const float* blin = (const float*)d_in[14];
  float* out = (float*)d_out;

  unsigned int*   cnt  = (unsigned int*)d_ws;
  unsigned short* ring = (unsigned short*)((char*)d_ws + 8192);
  // ws usage: 8192 B flags (prod @0, cons @4096) + 3*16*4*8192 B ring = ~1.5 MB

  hipMemsetAsync(d_ws, 0, 8192, stream);
  hipMemsetAsync(d_out, 0, (size_t)out_size * sizeof(float), stream);

  lstm3_kernel<<<dim3(3 * NG), dim3(1024), 0, stream>>>(
      xin, Wi1, Wh1, bi1, bh1, Wi2, Wh2, bi2, bh2,
      Wi3, Wh3, bi3, bh3, Wlin, blin, out, cnt, ring);
}

// Round 11
// 1954.255 us; speedup vs baseline: 7.4182x; 7.4182x over previous
//
#include <hip/hip_runtime.h>
#include <stdint.h>

// 3-layer LSTM (H=256, B=256, T=512), persistent pipelined kernel.
// Partition: per layer, GB=8 batch-groups (32 rows) x GH=8 hidden-groups (32 units)
//   -> 192 workgroups of 512 threads (8 waves). K1 base (proven 1663 us):
// Waves: (tau, mh) = (gate i/f/g/o, batch half); weight slice [32 rows x 512 K]
// as bf16 MFMA B-fragments in 128 regs (held resident — K1's FETCH=120 MB
// proves no remat). h via global bf16 ring (depth 4), agent-scope sc0 sc1.
//
// R12 = K1 + three surgical sync-chain trims (R11 post-mortem: whole-layer-
// per-CU is impossible — 512 KB weights = the whole CU register file — so the
// cross-WG h-broadcast is structural; beat ~8800cy ≈ serialized ~900cy LLC
// hops + congestion. Trim the hops):
//  (a) per-producer SLOT flags (R6-verified logic): slot[l][g][j] = steps done,
//      published by plain relaxed agent store — removes the 8-sibling RMW
//      serialization on one counter line.
//  (b) one lane per producer slot (tid 0..23): 8-way parallel observe instead
//      of a single poller on an aggregated counter — cuts the observe tail.
//  (c) l==2 output-head atomicAdd moved AFTER the flag publish: its ~900cy
//      drain leaves the critical chain and hides under the next spin window
//      (out is never read by any WG; final drain at kernel end).
// Everything else byte-identical to K1: staging map, LDS fragment-major map,
// MFMA, gl[] exchange, combine, ring layout.

#define Hd 256
#define Bd 256
#define Td 512
#define RING 4
#define GH 8
#define GB 8
#define GPAD 32   // uints per (l,g) slot group: 8 slots + pad to 128 B

typedef __attribute__((ext_vector_type(8))) short short8;
typedef __attribute__((ext_vector_type(4))) float floatx4;
typedef __attribute__((ext_vector_type(4))) unsigned int uintx4;

__device__ __forceinline__ unsigned short f2bf(float f) {
  union { float f; unsigned int u; } v; v.f = f;
  return (unsigned short)((v.u + 0x7fffu + ((v.u >> 16) & 1u)) >> 16);
}
__device__ __forceinline__ float sigm(float x) { return 1.0f / (1.0f + __expf(-x)); }
__device__ __forceinline__ float tanhfast(float x) { return 2.0f / (1.0f + __expf(-2.0f * x)) - 1.0f; }

__device__ __forceinline__ void spin_relaxed(unsigned int* p, unsigned int v) {
  while (__hip_atomic_load(p, __ATOMIC_RELAXED, __HIP_MEMORY_SCOPE_AGENT) < v) { }
}

__global__ __launch_bounds__(512, 2) void lstm3_kernel(
    const float* __restrict__ xin,
    const float* __restrict__ Wi1, const float* __restrict__ Wh1,
    const float* __restrict__ bi1, const float* __restrict__ bh1,
    const float* __restrict__ Wi2, const float* __restrict__ Wh2,
    const float* __restrict__ bi2, const float* __restrict__ bh2,
    const float* __restrict__ Wi3, const float* __restrict__ Wh3,
    const float* __restrict__ bi3, const float* __restrict__ bh3,
    const float* __restrict__ Wlin, const float* __restrict__ blin,
    float* __restrict__ out,                // [B][T], pre-zeroed
    unsigned int* __restrict__ cnt,         // [3*GB*GPAD] slot flags, pre-zeroed
    unsigned short* __restrict__ ring)      // [3][RING][B][H] bf16
{
  __shared__ float gl[4][32][33];   // [gate][local row][local unit(+pad)]
  __shared__ uintx4 hbuf[2][1024];  // [0]=up h(t), [1]=own h(t-1); fragment-major
                                    // chunk cidx = kc*128 + row*4 + quad (16B each)

  const int bid = blockIdx.x;
  const int j   = bid / 24;         // hidden group 0..7
  const int rem = bid - j * 24;
  const int l   = rem >> 3;         // layer 0..2
  const int g   = rem & 7;          // batch group 0..7 (bid%8 -> same XCD, perf only)

  const int tid  = threadIdx.x;
  const int lane = tid & 63;
  const int wave = tid >> 6;
  const int tau  = wave & 3;        // gate: 0=i 1=f 2=g 3=o
  const int mh   = wave >> 2;       // batch half
  const int quad = lane >> 4;
  const int l15  = lane & 15;

  const int ubase = j * 32;
  const int rbase = g * 32;

  const float* Wpi = (l == 1) ? Wi2 : Wi3;
  const float* Wph = (l == 0) ? Wh1 : ((l == 1) ? Wh2 : Wh3);
  const float* bi  = (l == 0) ? bi1 : ((l == 1) ? bi2 : bi3);
  const float* bh  = (l == 0) ? bh1 : ((l == 1) ? bh2 : bh3);

  // ---- one-time: weight slice -> bf16 B-fragments in registers ----
  short8 breg[2][16];
  {
    const int koff = quad * 8;
    #pragma unroll
    for (int nt = 0; nt < 2; ++nt) {
      const int grow = tau * Hd + ubase + nt * 16 + l15;
      #pragma unroll
      for (int kc = 0; kc < 16; ++kc) {
        short8 v = {0, 0, 0, 0, 0, 0, 0, 0};
        const float* src = nullptr;
        if (kc < 8) { if (l != 0) src = Wpi + (size_t)grow * Hd + kc * 32 + koff; }
        else        { src = Wph + (size_t)grow * Hd + (kc - 8) * 32 + koff; }
        if (src) {
          #pragma unroll
          for (int e = 0; e < 8; ++e) v[e] = (short)f2bf(src[e]);
        }
        breg[nt][kc] = v;
      }
    }
  }

  // ---- combine-phase per-thread constants ----
  const int clrow = tid >> 4;
  const int cu0   = (tid & 15) * 2;
  float bsum[4][2], wiv[4][2], wlv[2];
  #pragma unroll
  for (int tt = 0; tt < 4; ++tt) {
    #pragma unroll
    for (int du = 0; du < 2; ++du) {
      const int gg = tt * Hd + ubase + cu0 + du;
      bsum[tt][du] = bi[gg] + bh[gg];
      wiv[tt][du]  = (l == 0) ? Wi1[gg] : 0.0f;
    }
  }
  wlv[0] = (l == 2) ? Wlin[ubase + cu0]     : 0.0f;
  wlv[1] = (l == 2) ? Wlin[ubase + cu0 + 1] : 0.0f;
  const float bl0 = (l == 2 && j == 0) ? blin[0] : 0.0f;

  float cst0 = 0.0f, cst1 = 0.0f;

  // slot flags: group (l,g) at cnt + (l*GB+g)*GPAD, 8 uints (one per j)
  unsigned int* myS = cnt + (l * GB + g) * GPAD;
  unsigned int* upS = cnt + ((l - 1) * GB + g) * GPAD;   // deref only if l>0
  unsigned int* dnS = cnt + ((l + 1) * GB + g) * GPAD;   // deref only if l<2
  unsigned short* ownR = ring + (size_t)l * RING * Bd * Hd;
  const unsigned short* upRb = ring + (size_t)(l - 1) * RING * Bd * Hd;

  const float* xrow = xin + (size_t)(rbase + clrow) * Td;

  // ---- staging geometry: thread -> two 16B chunks, LDS-linear (K1 map) ----
  // cidx = kc*128 + row*4 + quad ; lds byte = cidx*16 ; global byte in tile:
  //   o = row*512 + kc*64 + q*16
  const int c0 = tid;
  const int c1 = tid + 512;
  const int o0 = ((c0 >> 2) & 31) * 512 + (c0 >> 7) * 64 + (c0 & 3) * 16;
  const int o1 = ((c1 >> 2) & 31) * 512 + (c1 >> 7) * 64 + (c1 & 3) * 16;
  const int fragbase = (mh * 16 + l15) * 4 + quad;

  // zero own-h tile so t==0 reads h(-1)=0 (ordered by barriers of step 0)
  {
    uintx4 z = {0u, 0u, 0u, 0u};
    hbuf[1][c0] = z;
    hbuf[1][c1] = z;
  }

  for (int t = 0; t < Td; ++t) {
    // ---- waits: one lane per producer slot (8-way parallel observe) ----
    {
      bool active = false; unsigned int* p = nullptr; unsigned need = 0;
      if (tid < 8)       { active = (t > 0);                p = myS + tid;        need = t; }
      else if (tid < 16) { active = (l > 0);                p = upS + (tid - 8);  need = t + 1; }
      else if (tid < 24) { active = (l < 2) && (t >= RING); p = dnS + (tid - 16); need = t - RING + 1; }
      if (active) spin_relaxed(p, need);
    }
    __syncthreads();

    // ---- stage h tiles -> LDS: 16B coherent loads, issue-all then one wait ----
    uintx4 u0, u1, v0, v1;
    if (l != 0) {
      const char* upReg = (const char*)(upRb + (size_t)(t & (RING - 1)) * Bd * Hd
                                        + (size_t)rbase * Hd);
      asm volatile("global_load_dwordx4 %0, %1, off sc0 sc1"
                   : "=&v"(u0) : "v"(upReg + o0));
      asm volatile("global_load_dwordx4 %0, %1, off sc0 sc1"
                   : "=&v"(u1) : "v"(upReg + o1));
    }
    if (t != 0) {
      const char* ownReg = (const char*)(ownR + (size_t)((t + RING - 1) & (RING - 1)) * Bd * Hd
                                         + (size_t)rbase * Hd);
      asm volatile("global_load_dwordx4 %0, %1, off sc0 sc1"
                   : "=&v"(v0) : "v"(ownReg + o0));
      asm volatile("global_load_dwordx4 %0, %1, off sc0 sc1"
                   : "=&v"(v1) : "v"(ownReg + o1));
    }
    asm volatile("s_waitcnt vmcnt(0)" ::: "memory");
    if (l != 0) { hbuf[0][c0] = u0; hbuf[0][c1] = u1; }
    if (t != 0) { hbuf[1][c0] = v0; hbuf[1][c1] = v1; }
    __syncthreads();

    // ---- A-fragments from LDS (K1 fragment-major map) ----
    short8 av[16];
    if (l != 0) {
      #pragma unroll
      for (int kc = 0; kc < 8; ++kc)
        av[kc] = *reinterpret_cast<const short8*>(&hbuf[0][kc * 128 + fragbase]);
    }
    #pragma unroll
    for (int kc = 0; kc < 8; ++kc)
      av[8 + kc] = *reinterpret_cast<const short8*>(&hbuf[1][kc * 128 + fragbase]);

    // ---- MFMA: gates[32 rows][32 units] for gate-type tau ----
    floatx4 acc0 = {0.f, 0.f, 0.f, 0.f};
    floatx4 acc1 = {0.f, 0.f, 0.f, 0.f};
    if (l != 0) {
      #pragma unroll
      for (int kc = 0; kc < 8; ++kc) {
        acc0 = __builtin_amdgcn_mfma_f32_16x16x32_bf16(av[kc], breg[0][kc], acc0, 0, 0, 0);
        acc1 = __builtin_amdgcn_mfma_f32_16x16x32_bf16(av[kc], breg[1][kc], acc1, 0, 0, 0);
      }
    }
    #pragma unroll
    for (int kc = 8; kc < 16; ++kc) {
      acc0 = __builtin_amdgcn_mfma_f32_16x16x32_bf16(av[kc], breg[0][kc], acc0, 0, 0, 0);
      acc1 = __builtin_amdgcn_mfma_f32_16x16x32_bf16(av[kc], breg[1][kc], acc1, 0, 0, 0);
    }

    // C layout: col(unit) = lane&15, row = quad*4 + reg
    {
      const int lr = mh * 16 + quad * 4;
      #pragma unroll
      for (int r2 = 0; r2 < 4; ++r2) {
        gl[tau][lr + r2][l15]      = acc0[r2];
        gl[tau][lr + r2][16 + l15] = acc1[r2];
      }
    }
    __syncthreads();

    // ---- combine: 1 row x 2 units per thread, fp32 LSTM cell math ----
    float h0, h1;
    {
      const float xv = (l == 0) ? xrow[t] : 0.0f;
      float pi = gl[0][clrow][cu0] + bsum[0][0] + xv * wiv[0][0];
      float pf = gl[1][clrow][cu0] + bsum[1][0] + xv * wiv[1][0];
      float pg = gl[2][clrow][cu0] + bsum[2][0] + xv * wiv[2][0];
      float po = gl[3][clrow][cu0] + bsum[3][0] + xv * wiv[3][0];
      float ii = sigm(pi), ff = sigm(pf), gv = tanhfast(pg), oo = sigm(po);
      cst0 = ff * cst0 + ii * gv;
      h0 = oo * tanhfast(cst0);
      pi = gl[0][clrow][cu0 + 1] + bsum[0][1] + xv * wiv[0][1];
      pf = gl[1][clrow][cu0 + 1] + bsum[1][1] + xv * wiv[1][1];
      pg = gl[2][clrow][cu0 + 1] + bsum[2][1] + xv * wiv[2][1];
      po = gl[3][clrow][cu0 + 1] + bsum[3][1] + xv * wiv[3][1];
      ii = sigm(pi); ff = sigm(pf); gv = tanhfast(pg); oo = sigm(po);
      cst1 = ff * cst1 + ii * gv;
      h1 = oo * tanhfast(cst1);
    }

    // store h pair (LLC write-through, relaxed)
    {
      unsigned short* dst = ownR + (size_t)(t & (RING - 1)) * Bd * Hd
                          + (size_t)(rbase + clrow) * Hd + ubase + cu0;
      const unsigned int packed = (unsigned int)f2bf(h0) | ((unsigned int)f2bf(h1) << 16);
      __hip_atomic_store((unsigned int*)dst, packed, __ATOMIC_RELAXED,
                         __HIP_MEMORY_SCOPE_AGENT);
    }

    __syncthreads();   // barrier drains vmcnt: all h-stores at LLC before publish
    if (tid == 0) {
      __hip_atomic_store(myS + j, (unsigned int)(t + 1), __ATOMIC_RELAXED,
                         __HIP_MEMORY_SCOPE_AGENT);
    }

    // ---- output head AFTER publish: its drain hides under the next spin ----
    if (l == 2) {
      float pr = wlv[0] * h0 + wlv[1] * h1;
      pr += __shfl_xor(pr, 8);
      pr += __shfl_xor(pr, 4);
      pr += __shfl_xor(pr, 2);
      pr += __shfl_xor(pr, 1);
      if ((tid & 15) == 0) {
        atomicAdd(&out[(size_t)(rbase + clrow) * Td + t], pr + bl0);
      }
    }
  }
}

extern "C" void kernel_launch(void* const* d_in, const int* in_sizes, int n_in,
                              void* d_out, int out_size, void* d_ws, size_t ws_size,
                              hipStream_t stream) {
  const float* xin  = (const float*)d_in[0];
  const float* Wi1  = (const float*)d_in[1];
  const float* Wh1  = (const float*)d_in[2];
  const float* bi1  = (const float*)d_in[3];
  const float* bh1  = (const float*)d_in[4];
  const float* Wi2  = (const float*)d_in[5];
  const float* Wh2  = (const float*)d_in[6];
  const float* bi2  = (const float*)d_in[7];
  const float* bh2  = (const float*)d_in[8];
  const float* Wi3  = (const float*)d_in[9];
  const float* Wh3  = (const float*)d_in[10];
  const float* bi3  = (const float*)d_in[11];
  const float* bh3  = (const float*)d_in[12];
  const float* Wlin = (const float*)d_in[13];
  const float* blin = (const float*)d_in[14];
  float* out = (float*)d_out;

  unsigned int*   cnt  = (unsigned int*)d_ws;
  unsigned short* ring = (unsigned short*)((char*)d_ws + 4096);
  // ws usage: 4096 B slot flags (3*8 groups x 128 B) + ~1.5 MB rings

  hipMemsetAsync(d_ws, 0, 4096, stream);
  hipMemsetAsync(d_out, 0, (size_t)out_size * sizeof(float), stream);

  lstm3_kernel<<<dim3(3 * GB * GH), dim3(512), 0, stream>>>(
      xin, Wi1, Wh1, bi1, bh1, Wi2, Wh2, bi2, bh2,
      Wi3, Wh3, bi3, bh3, Wlin, blin, out, cnt, ring);
}